// Round 4
// baseline (282.460 us; speedup 1.0000x reference)
//
#include <hip/hip_runtime.h>
#include <math.h>

#define HW    9216
#define KJ    17
#define BATCH 128
#define TOPK  8
#define NROW  (BATCH * KJ)   // 2176

// Fused kernel. Phase 1 (all 2176 blocks): per-(b,k) weighted MSE row sum —
// EXACT R3 structure (4-deep rotating prefetch ring, 60.6us, verified).
// Phase 2 (last finishing block only): per-sample top-8-of-17 + batch mean.
//
// History: R0 {18-deep burst, 37% occ}, R1 {shallow, high occ}, R3 {8-deep
// ring, 50% occ} ALL = 60.5us / 2.65 TB/s total-read / FETCH = exactly one
// tensor. Phase-1 service rate is structure-insensitive; this round attacks
// the OTHER term of dur_us: the ~116us residue (k2 dispatch + launch gaps),
// by removing the second launch entirely.
//
// Cross-XCD correctness (per-XCD L2s are NOT coherent): pj is published with
// device-scope atomicExch (performed at the coherent point), ordered before
// the counter atomicAdd by __threadfence(); the reader re-reads pj with
// atomicAdd(p, 0.0f) (coherent read) — no reliance on plain-load visibility.
// Counter correctness without assuming ws zeroing each iteration:
// (prev+1) % NROW == 0 fires exactly once per launch as long as ws was
// zeroed at least once before first use (harness reset() memsets ws).
__global__ __launch_bounds__(256, 6) void fused_ohkm(
    const float* __restrict__ outp, const float* __restrict__ tgt,
    const float* __restrict__ tw, float* __restrict__ pj,
    unsigned* __restrict__ counter, float* __restrict__ result)
{
    const int row = blockIdx.x;            // b*KJ + k
    const float4* o4 = (const float4*)(outp + (size_t)row * HW);
    const float4* t4 = (const float4*)(tgt  + (size_t)row * HW);
    const int tid = threadIdx.x;

    // ---- Phase 1: row sum of squared diff (R3-identical) ----
    float4 ob[4], tb[4];
#pragma unroll
    for (int j = 0; j < 4; ++j) {
        ob[j] = o4[tid + j * 256];
        tb[j] = t4[tid + j * 256];
    }

    float acc = 0.f;
#pragma unroll
    for (int j = 0; j < 9; ++j) {
        const float4 o = ob[j & 3];
        const float4 t = tb[j & 3];
        if (j + 4 < 9) {
            ob[j & 3] = o4[tid + (j + 4) * 256];
            tb[j & 3] = t4[tid + (j + 4) * 256];
        }
        const float d0 = o.x - t.x;
        const float d1 = o.y - t.y;
        const float d2 = o.z - t.z;
        const float d3 = o.w - t.w;
        acc = fmaf(d0, d0, acc);
        acc = fmaf(d1, d1, acc);
        acc = fmaf(d2, d2, acc);
        acc = fmaf(d3, d3, acc);
    }

#pragma unroll
    for (int off = 32; off > 0; off >>= 1)
        acc += __shfl_down(acc, off, 64);

    __shared__ float smem[4];
    __shared__ int   sLast;
    __shared__ float pjs[NROW];            // 8704 B — phase-2 staging
    const int wave = tid >> 6;
    if ((tid & 63) == 0) smem[wave] = acc;
    __syncthreads();
    if (tid == 0) {
        const float w = tw[row];
        const float tot = (smem[0] + smem[1] + smem[2] + smem[3])
                          * w * w * (1.0f / (float)HW);
        atomicExch(&pj[row], tot);         // publish at coherent point
        __threadfence();                   // pj-exch ordered before counter-add
        const unsigned prev = atomicAdd(counter, 1u);
        sLast = (((prev + 1u) % (unsigned)NROW) == 0u) ? 1 : 0;
    }
    __syncthreads();                       // broadcast sLast (block-uniform)
    if (!sLast) return;

    // ---- Phase 2: last block only — top-8 of 17 per sample, batch mean ----
    __threadfence();
    // Cooperative coherent re-read of all 2176 pj values into LDS.
    for (int i = tid; i < NROW; i += 256)
        pjs[i] = atomicAdd(&pj[i], 0.0f);  // coherent read (returns old)
    __syncthreads();

    float s = 0.f;
    if (tid < BATCH) {                     // one sample per thread, 2 waves
        float v[KJ];
#pragma unroll
        for (int k = 0; k < KJ; ++k) v[k] = pjs[tid * KJ + k]; // stride 17: conflict-free
#pragma unroll
        for (int t = 0; t < TOPK; ++t) {
            float m = v[0];
#pragma unroll
            for (int k = 1; k < KJ; ++k) m = fmaxf(m, v[k]);
            s += m;
            // remove exactly the FIRST element equal to m (tie-safe top_k)
            bool removed = false;
#pragma unroll
            for (int k = 0; k < KJ; ++k) {
                const bool hit = (!removed) && (v[k] == m);
                v[k] = hit ? -INFINITY : v[k];
                removed = removed || hit;
            }
        }
    }

#pragma unroll
    for (int off = 32; off > 0; off >>= 1)
        s += __shfl_down(s, off, 64);      // waves 2,3 reduce zeros

    __syncthreads();                       // smem reuse after phase-1 reads
    if ((tid & 63) == 0) smem[wave] = s;
    __syncthreads();
    if (tid == 0)
        result[0] = (smem[0] + smem[1]) * (1.0f / (float)(BATCH * TOPK));
}

extern "C" void kernel_launch(void* const* d_in, const int* in_sizes, int n_in,
                              void* d_out, int out_size, void* d_ws, size_t ws_size,
                              hipStream_t stream) {
    const float* outp = (const float*)d_in[0];   // [128,17,96,96]
    const float* tgt  = (const float*)d_in[1];   // [128,17,96,96]
    const float* tw   = (const float*)d_in[2];   // [128,17,1]
    float* result = (float*)d_out;               // scalar
    float* pj = (float*)d_ws;                    // [2176] per-joint MSE
    unsigned* counter = (unsigned*)(pj + NROW);  // 1 u32 completion counter

    fused_ohkm<<<NROW, 256, 0, stream>>>(outp, tgt, tw, pj, counter, result);
}

// Round 5
// 179.136 us; speedup vs baseline: 1.5768x; 1.5768x over previous
//
#include <hip/hip_runtime.h>
#include <math.h>

#define HW     9216
#define KJ     17
#define BATCH  128
#define TOPK   8
#define NROW   (BATCH * KJ)      // 2176
#define CHUNK  3                 // chunk-blocks per row
#define CFLOAT (HW / CHUNK)      // 3072 floats per chunk (12 KB, f4-aligned)

// R5: two-kernel structure reverted (R4 fusion: 170us — cross-XCD fence+atomic
// stalls every block; residue proved FIXED ~114us harness overhead, k2 free).
// R0/R1/R3 all hit 60.5us with grid 2176x4waves = 1.06 machine-generations:
// time-avg occupancy 50% == pure ramp/drain triangle, and each block's
// reduce/store tail can't overlap later work. This round: 3 chunk-blocks per
// row -> grid 6528 (3.2 generations), 6 loads/thread all in flight, partials
// summed in k2. Tests the shallow-grid + per-block-tail theory.
__global__ __launch_bounds__(256, 6) void per_joint_partial(
    const float* __restrict__ outp, const float* __restrict__ tgt,
    float* __restrict__ pj3)
{
    const int g   = blockIdx.x;          // row * CHUNK + c
    const int row = g / CHUNK;
    const int c   = g - row * CHUNK;
    const size_t base = (size_t)row * HW + (size_t)c * CFLOAT;
    const float4* o4 = (const float4*)(outp + base);
    const float4* t4 = (const float4*)(tgt  + base);
    const int tid = threadIdx.x;

    // 3 float4 per tensor per thread — all 6 loads issued up front.
    float4 o0 = o4[tid];
    float4 t0 = t4[tid];
    float4 o1 = o4[tid + 256];
    float4 t1 = t4[tid + 256];
    float4 o2 = o4[tid + 512];
    float4 t2 = t4[tid + 512];

    float acc = 0.f;
    float d;
    d = o0.x - t0.x; acc = fmaf(d, d, acc);
    d = o0.y - t0.y; acc = fmaf(d, d, acc);
    d = o0.z - t0.z; acc = fmaf(d, d, acc);
    d = o0.w - t0.w; acc = fmaf(d, d, acc);
    d = o1.x - t1.x; acc = fmaf(d, d, acc);
    d = o1.y - t1.y; acc = fmaf(d, d, acc);
    d = o1.z - t1.z; acc = fmaf(d, d, acc);
    d = o1.w - t1.w; acc = fmaf(d, d, acc);
    d = o2.x - t2.x; acc = fmaf(d, d, acc);
    d = o2.y - t2.y; acc = fmaf(d, d, acc);
    d = o2.z - t2.z; acc = fmaf(d, d, acc);
    d = o2.w - t2.w; acc = fmaf(d, d, acc);

    // wave64 shuffle reduce
#pragma unroll
    for (int off = 32; off > 0; off >>= 1)
        acc += __shfl_down(acc, off, 64);

    __shared__ float smem[4];
    if ((tid & 63) == 0) smem[tid >> 6] = acc;
    __syncthreads();
    if (tid == 0)
        pj3[g] = smem[0] + smem[1] + smem[2] + smem[3];   // raw partial SSD
}

// Kernel 2: sum 3 partials per row, apply w^2/HW, top-8-of-17, batch mean.
// 1 block, 128 threads (one sample each). ~26 KB reads: L2/launch-latency
// bound, measured-free relative to the ~114us fixed harness residue.
__global__ __launch_bounds__(128) void ohkm_reduce(
    const float* __restrict__ pj3, const float* __restrict__ tw,
    float* __restrict__ result)
{
    const int b = threadIdx.x;   // 0..127
    float v[KJ];
#pragma unroll
    for (int k = 0; k < KJ; ++k) {
        const int r = b * KJ + k;
        const float s3 = pj3[r * CHUNK] + pj3[r * CHUNK + 1] + pj3[r * CHUNK + 2];
        const float w  = tw[r];
        v[k] = s3 * w * w * (1.0f / (float)HW);
    }

    float s = 0.f;
#pragma unroll
    for (int t = 0; t < TOPK; ++t) {
        float m = v[0];
#pragma unroll
        for (int k = 1; k < KJ; ++k) m = fmaxf(m, v[k]);
        s += m;
        // remove exactly the FIRST element equal to m (tie-safe top_k semantics)
        bool removed = false;
#pragma unroll
        for (int k = 0; k < KJ; ++k) {
            const bool hit = (!removed) && (v[k] == m);
            v[k] = hit ? -INFINITY : v[k];
            removed = removed || hit;
        }
    }

    // 128 threads = 2 waves
#pragma unroll
    for (int off = 32; off > 0; off >>= 1)
        s += __shfl_down(s, off, 64);

    __shared__ float smem[2];
    if ((b & 63) == 0) smem[b >> 6] = s;
    __syncthreads();
    if (b == 0)
        result[0] = (smem[0] + smem[1]) * (1.0f / (float)(BATCH * TOPK));
}

extern "C" void kernel_launch(void* const* d_in, const int* in_sizes, int n_in,
                              void* d_out, int out_size, void* d_ws, size_t ws_size,
                              hipStream_t stream) {
    const float* outp = (const float*)d_in[0];   // [128,17,96,96]
    const float* tgt  = (const float*)d_in[1];   // [128,17,96,96]
    const float* tw   = (const float*)d_in[2];   // [128,17,1]
    float* result = (float*)d_out;               // scalar
    float* pj3 = (float*)d_ws;                   // [NROW*CHUNK] partial SSDs

    per_joint_partial<<<NROW * CHUNK, 256, 0, stream>>>(outp, tgt, pj3);
    ohkm_reduce<<<1, 128, 0, stream>>>(pj3, tw, result);
}